// Round 2
// 8303.748 us; speedup vs baseline: 2.1372x; 2.1372x over previous
//
#include <hip/hip_runtime.h>

typedef __attribute__((ext_vector_type(8))) short bf16x8;   // 8 bf16 bit-patterns (4 VGPRs)
typedef __attribute__((ext_vector_type(4))) float f32x4;

// ---- round-to-nearest-even fp32 -> bf16, and the 2-term RNE split ----
__device__ __forceinline__ unsigned short bf_rne(float a) {
  unsigned int u = __float_as_uint(a);
  return (unsigned short)((u + 0x7fffu + ((u >> 16) & 1u)) >> 16);
}
__device__ __forceinline__ float from_bf(unsigned short h) {
  return __uint_as_float((unsigned int)h << 16);
}
__device__ __forceinline__ void split2(float x, unsigned short& h, unsigned short& l) {
  h = bf_rne(x);
  float lo = x - from_bf(h);   // exact (Sterbenz: hi within half-ulp of x)
  l = bf_rne(lo);
}
__device__ __forceinline__ unsigned int pack2(unsigned short a, unsigned short b) {
  return (unsigned int)a | ((unsigned int)b << 16);
}

// ---------------- im2col + bf16 hi/lo split: x[B,3,224,224] -> ph/pl[6272,768] ----------------
__global__ __launch_bounds__(256) void im2col_split(const float* __restrict__ x,
                                                    unsigned short* __restrict__ ph,
                                                    unsigned short* __restrict__ pl) {
  int idx = blockIdx.x * 256 + threadIdx.x;
  if (idx >= 6272 * 192) return;
  int k4 = idx % 192, r = idx / 192;
  int k = k4 * 4;
  int c = k >> 8, py = (k >> 4) & 15, px = k & 15;
  int t = r % 196, b = r / 196;
  int gy = t / 14, gx = t % 14;
  float4 f = *(const float4*)(x + (((size_t)(b * 3 + c) * 224 + gy * 16 + py) * 224 + gx * 16 + px));
  unsigned short h0, l0, h1, l1, h2, l2, h3, l3;
  split2(f.x, h0, l0); split2(f.y, h1, l1); split2(f.z, h2, l2); split2(f.w, h3, l3);
  uint2 hp, lp;
  hp.x = pack2(h0, h1); hp.y = pack2(h2, h3);
  lp.x = pack2(l0, l1); lp.y = pack2(l2, l3);
  *(uint2*)(ph + (size_t)r * 768 + k) = hp;
  *(uint2*)(pl + (size_t)r * 768 + k) = lp;
}

// ---------------- generic fp32 -> bf16 hi/lo split (weights, attention output) ----------------
__global__ __launch_bounds__(256) void split_f32(const float* __restrict__ in,
                                                 unsigned short* __restrict__ hi,
                                                 unsigned short* __restrict__ lo, int n4) {
  int i = blockIdx.x * 256 + threadIdx.x;
  if (i >= n4) return;
  float4 f = ((const float4*)in)[i];
  unsigned short h0, l0, h1, l1, h2, l2, h3, l3;
  split2(f.x, h0, l0); split2(f.y, h1, l1); split2(f.z, h2, l2); split2(f.w, h3, l3);
  uint2 hp, lp;
  hp.x = pack2(h0, h1); hp.y = pack2(h2, h3);
  lp.x = pack2(l0, l1); lp.y = pack2(l2, l3);
  *(uint2*)(hi + (size_t)i * 4) = hp;
  *(uint2*)(lo + (size_t)i * 4) = lp;
}

// ---------------- assemble h[6304,768] fp32 = [cls | pe+pos] ----------------
__global__ __launch_bounds__(256) void assemble_h(const float* __restrict__ pe,
                                                  const float* __restrict__ pos,
                                                  const float* __restrict__ cls,
                                                  float* __restrict__ h) {
  int idx = blockIdx.x * 256 + threadIdx.x;
  if (idx >= 6304 * 192) return;
  int d4 = idx % 192, row = idx / 192;
  int t = row % 197, b = row / 197;
  int d = d4 * 4;
  float4 v;
  if (t == 0) {
    v = *(const float4*)(cls + d);
  } else {
    v = *(const float4*)(pe + ((size_t)(b * 196 + (t - 1))) * 768 + d);
    float4 p = *(const float4*)(pos + (size_t)(t - 1) * 768 + d);
    v.x += p.x; v.y += p.y; v.z += p.z; v.w += p.w;
  }
  *(float4*)(h + (size_t)row * 768 + d) = v;
}

// ---------------- LayerNorm (row=768) fp32 -> fp32 (final LN only) ----------------
__global__ __launch_bounds__(256) void layernorm_f32(const float* __restrict__ x,
                                                     const float* __restrict__ w,
                                                     const float* __restrict__ b,
                                                     float* __restrict__ y, long long xstride) {
  long long row = blockIdx.x;
  const float* xr = x + row * xstride;
  int tid = threadIdx.x;
  float v0 = xr[tid], v1 = xr[tid + 256], v2 = xr[tid + 512];
  float s = v0 + v1 + v2;
  float ss = v0 * v0 + v1 * v1 + v2 * v2;
  for (int off = 32; off; off >>= 1) {
    s += __shfl_xor(s, off);
    ss += __shfl_xor(ss, off);
  }
  __shared__ float red[8];
  int wv = tid >> 6;
  if ((tid & 63) == 0) { red[wv] = s; red[wv + 4] = ss; }
  __syncthreads();
  s = red[0] + red[1] + red[2] + red[3];
  ss = red[4] + red[5] + red[6] + red[7];
  float mean = s * (1.0f / 768.0f);
  float var = ss * (1.0f / 768.0f) - mean * mean;
  float rstd = rsqrtf(var + 1e-5f);
  float* yr = y + row * 768;
  yr[tid] = (v0 - mean) * rstd * w[tid] + b[tid];
  yr[tid + 256] = (v1 - mean) * rstd * w[tid + 256] + b[tid + 256];
  yr[tid + 512] = (v2 - mean) * rstd * w[tid + 512] + b[tid + 512];
}

// ---------------- LayerNorm (row=768) fp32 -> bf16 hi/lo split ----------------
__global__ __launch_bounds__(256) void layernorm_split(const float* __restrict__ x,
                                                       const float* __restrict__ w,
                                                       const float* __restrict__ b,
                                                       unsigned short* __restrict__ yh,
                                                       unsigned short* __restrict__ yl) {
  long long row = blockIdx.x;
  const float* xr = x + row * 768;
  int tid = threadIdx.x;
  float v0 = xr[tid], v1 = xr[tid + 256], v2 = xr[tid + 512];
  float s = v0 + v1 + v2;
  float ss = v0 * v0 + v1 * v1 + v2 * v2;
  for (int off = 32; off; off >>= 1) {
    s += __shfl_xor(s, off);
    ss += __shfl_xor(ss, off);
  }
  __shared__ float red[8];
  int wv = tid >> 6;
  if ((tid & 63) == 0) { red[wv] = s; red[wv + 4] = ss; }
  __syncthreads();
  s = red[0] + red[1] + red[2] + red[3];
  ss = red[4] + red[5] + red[6] + red[7];
  float mean = s * (1.0f / 768.0f);
  float var = ss * (1.0f / 768.0f) - mean * mean;
  float rstd = rsqrtf(var + 1e-5f);
  unsigned short* yhr = yh + row * 768;
  unsigned short* ylr = yl + row * 768;
#pragma unroll
  for (int u = 0; u < 3; u++) {
    int c = tid + u * 256;
    float v = (u == 0 ? v0 : (u == 1 ? v1 : v2));
    float o = (v - mean) * rstd * w[c] + b[c];
    unsigned short hh, ll;
    split2(o, hh, ll);
    yhr[c] = hh;
    ylr[c] = ll;
  }
}

// ---------------- bf16x3 MFMA GEMM: C = act(A@W^T + bias) (+Res) ----------------
// A = Ah+Al [M,lda] bf16 hi/lo; W = Wh+Wl [N,ldw]; emulated-fp32 via 3 MFMA products.
// flags: 1=gelu, 2=bias, 4=residual, 8=split bf16 output (Chi/Clo) instead of fp32 C.
// Tile 128x128, BK=32, 4 waves, each wave owns a 64x64 quadrant = 4x4 16x16 frags.
// LDS: [row][slot^((row>>1)&3)] XOR-swizzle -> 2-way (free) on ds_read_b128 frag loads.
__global__ __launch_bounds__(256, 2) void gemm_bf16x3(
    const unsigned short* __restrict__ Ah, const unsigned short* __restrict__ Al,
    const unsigned short* __restrict__ Wh, const unsigned short* __restrict__ Wl,
    const float* __restrict__ bias, const float* __restrict__ Res,
    float* __restrict__ C, unsigned short* __restrict__ Chi, unsigned short* __restrict__ Clo,
    int M, int N, int K, int lda, int ldw, int ldc, int flags) {
  __shared__ unsigned short As_h[128 * 32], As_l[128 * 32], Bs_h[128 * 32], Bs_l[128 * 32];
  const int tid = threadIdx.x;
  const int lane = tid & 63, wv = tid >> 6;
  const int wr = wv >> 1, wc = wv & 1;
  const int m0 = blockIdx.y * 128, n0 = blockIdx.x * 128;

  // staging map: thread covers (row, slot) and (row+64, slot); slot = 8 contiguous bf16.
  const int srow = tid >> 2, ssl = tid & 3;
  int arow0 = m0 + srow;      if (arow0 >= M) arow0 = M - 1;
  int arow1 = m0 + srow + 64; if (arow1 >= M) arow1 = M - 1;
  const int brow0 = n0 + srow, brow1 = n0 + srow + 64;   // N is always a multiple of 128
  const unsigned short* pAh0 = Ah + (size_t)arow0 * lda + ssl * 8;
  const unsigned short* pAh1 = Ah + (size_t)arow1 * lda + ssl * 8;
  const unsigned short* pAl0 = Al + (size_t)arow0 * lda + ssl * 8;
  const unsigned short* pAl1 = Al + (size_t)arow1 * lda + ssl * 8;
  const unsigned short* pBh0 = Wh + (size_t)brow0 * ldw + ssl * 8;
  const unsigned short* pBh1 = Wh + (size_t)brow1 * ldw + ssl * 8;
  const unsigned short* pBl0 = Wl + (size_t)brow0 * ldw + ssl * 8;
  const unsigned short* pBl1 = Wl + (size_t)brow1 * ldw + ssl * 8;
  const int ps = ssl ^ ((srow >> 1) & 3);          // physical slot (same for row and row+64)
  const int w0 = srow * 32 + ps * 8, w1 = w0 + 64 * 32;

  // fragment read offsets (ushort units): row*32 + (kg^sx)*8, sx=((lane&15)>>1)&3
  const int kg = lane >> 4, r15 = lane & 15;
  const int fo = r15 * 32 + ((kg ^ ((r15 >> 1) & 3)) * 8);
  int aoff[4], boff[4];
#pragma unroll
  for (int i = 0; i < 4; i++) {
    aoff[i] = (wr * 64 + i * 16) * 32 + fo;
    boff[i] = (wc * 64 + i * 16) * 32 + fo;
  }

  f32x4 acc[4][4] = {};

  for (int k0 = 0; k0 < K; k0 += 32) {
    uint4 rAh0 = *(const uint4*)(pAh0 + k0);
    uint4 rAh1 = *(const uint4*)(pAh1 + k0);
    uint4 rAl0 = *(const uint4*)(pAl0 + k0);
    uint4 rAl1 = *(const uint4*)(pAl1 + k0);
    uint4 rBh0 = *(const uint4*)(pBh0 + k0);
    uint4 rBh1 = *(const uint4*)(pBh1 + k0);
    uint4 rBl0 = *(const uint4*)(pBl0 + k0);
    uint4 rBl1 = *(const uint4*)(pBl1 + k0);
    __syncthreads();
    *(uint4*)&As_h[w0] = rAh0; *(uint4*)&As_h[w1] = rAh1;
    *(uint4*)&As_l[w0] = rAl0; *(uint4*)&As_l[w1] = rAl1;
    *(uint4*)&Bs_h[w0] = rBh0; *(uint4*)&Bs_h[w1] = rBh1;
    *(uint4*)&Bs_l[w0] = rBl0; *(uint4*)&Bs_l[w1] = rBl1;
    __syncthreads();
    bf16x8 ah[4], al[4], bh[4], bl[4];
#pragma unroll
    for (int i = 0; i < 4; i++) {
      ah[i] = *(const bf16x8*)&As_h[aoff[i]];
      al[i] = *(const bf16x8*)&As_l[aoff[i]];
    }
#pragma unroll
    for (int j = 0; j < 4; j++) {
      bh[j] = *(const bf16x8*)&Bs_h[boff[j]];
      bl[j] = *(const bf16x8*)&Bs_l[boff[j]];
    }
#pragma unroll
    for (int i = 0; i < 4; i++)
#pragma unroll
      for (int j = 0; j < 4; j++) {
        acc[i][j] = __builtin_amdgcn_mfma_f32_16x16x32_bf16(ah[i], bh[j], acc[i][j], 0, 0, 0);
        acc[i][j] = __builtin_amdgcn_mfma_f32_16x16x32_bf16(ah[i], bl[j], acc[i][j], 0, 0, 0);
        acc[i][j] = __builtin_amdgcn_mfma_f32_16x16x32_bf16(al[i], bh[j], acc[i][j], 0, 0, 0);
      }
  }

  const bool gelu = flags & 1, hasb = flags & 2, hasr = flags & 4, sout = flags & 8;
#pragma unroll
  for (int j = 0; j < 4; j++) {
    int n = n0 + wc * 64 + j * 16 + r15;              // C/D col = lane&15
    float bj = hasb ? bias[n] : 0.0f;
#pragma unroll
    for (int i = 0; i < 4; i++) {
      int mbase = m0 + wr * 64 + i * 16 + kg * 4;     // C/D row = (lane>>4)*4 + reg
#pragma unroll
      for (int rr = 0; rr < 4; rr++) {
        int m = mbase + rr;
        if (m >= M) continue;
        float v = acc[i][j][rr] + bj;
        if (gelu) v = 0.5f * v * (1.0f + erff(v * 0.70710678118f));
        if (hasr) v += Res[(size_t)m * ldc + n];
        if (sout) {
          unsigned short hh, ll;
          split2(v, hh, ll);
          Chi[(size_t)m * ldc + n] = hh;
          Clo[(size_t)m * ldc + n] = ll;
        } else {
          C[(size_t)m * ldc + n] = v;
        }
      }
    }
  }
}

// ---------------- generic batched NT GEMM, pure fp32 (attention scores / PV) ----------------
__global__ __launch_bounds__(256) void gemm_f32(
    const float* A, const float* W, const float* bias, const float* Res, float* C,
    int M, int N, int K, int lda, int ldw, int ldc,
    long long offA1, long long offA2, long long offW1, long long offW2,
    long long offC1, long long offC2, int Hdiv, int flags) {
  int bz = blockIdx.z;
  int zh = bz / Hdiv, zl = bz - zh * Hdiv;
  A += (size_t)zh * offA1 + (size_t)zl * offA2;
  W += (size_t)zh * offW1 + (size_t)zl * offW2;
  long long coff = (long long)zh * offC1 + (long long)zl * offC2;

  __shared__ float As[16][68];
  __shared__ float Ws[16][68];
  int tid = threadIdx.x;
  int m0 = blockIdx.y * 64, n0 = blockIdx.x * 64;
  int tx = tid & 15, ty = tid >> 4;
  float acc[4][4] = {};
  int r = tid >> 2, c4 = (tid & 3) * 4;

  for (int k0 = 0; k0 < K; k0 += 16) {
    float4 av = {0.f, 0.f, 0.f, 0.f}, wv = {0.f, 0.f, 0.f, 0.f};
    if (m0 + r < M) av = *(const float4*)(A + (size_t)(m0 + r) * lda + k0 + c4);
    if (n0 + r < N) wv = *(const float4*)(W + (size_t)(n0 + r) * ldw + k0 + c4);
    __syncthreads();
    As[c4 + 0][r] = av.x; As[c4 + 1][r] = av.y; As[c4 + 2][r] = av.z; As[c4 + 3][r] = av.w;
    Ws[c4 + 0][r] = wv.x; Ws[c4 + 1][r] = wv.y; Ws[c4 + 2][r] = wv.z; Ws[c4 + 3][r] = wv.w;
    __syncthreads();
#pragma unroll
    for (int kk = 0; kk < 16; kk++) {
      float a[4], b[4];
#pragma unroll
      for (int i = 0; i < 4; i++) a[i] = As[kk][ty * 4 + i];
#pragma unroll
      for (int j = 0; j < 4; j++) b[j] = Ws[kk][tx * 4 + j];
#pragma unroll
      for (int i = 0; i < 4; i++)
#pragma unroll
        for (int j = 0; j < 4; j++) acc[i][j] += a[i] * b[j];
    }
  }

  bool gelu = flags & 1, hasb = flags & 2, hasr = flags & 4;
#pragma unroll
  for (int i = 0; i < 4; i++) {
    int m = m0 + ty * 4 + i;
    if (m >= M) continue;
#pragma unroll
    for (int j = 0; j < 4; j++) {
      int n = n0 + tx * 4 + j;
      if (n >= N) continue;
      float v = acc[i][j];
      if (hasb) v += bias[n];
      if (gelu) v = 0.5f * v * (1.0f + erff(v * 0.70710678118f));
      if (hasr) v += Res[coff + (size_t)m * ldc + n];
      C[coff + (size_t)m * ldc + n] = v;
    }
  }
}

// ---------------- softmax in-place on S[384*197,224] fp32 ----------------
__global__ __launch_bounds__(64) void softmax_f32(float* __restrict__ S) {
  size_t row = blockIdx.x;
  float* s = S + row * 224;
  int t = threadIdx.x;
  float v[4];
  float mx = -1e30f;
#pragma unroll
  for (int u = 0; u < 4; u++) {
    int j = t + u * 64;
    v[u] = (j < 197) ? s[j] * 8.0f : -1e30f;  // faithful bug: scores * sqrt(head_dim)
    mx = fmaxf(mx, v[u]);
  }
  for (int off = 32; off; off >>= 1) mx = fmaxf(mx, __shfl_xor(mx, off));
  float sum = 0.f;
#pragma unroll
  for (int u = 0; u < 4; u++) {
    int j = t + u * 64;
    v[u] = (j < 197) ? __expf(v[u] - mx) : 0.f;
    sum += v[u];
  }
  for (int off = 32; off; off >>= 1) sum += __shfl_xor(sum, off);
  float inv = 1.0f / sum;
#pragma unroll
  for (int u = 0; u < 4; u++) {
    int j = t + u * 64;
    if (j < 224) s[j] = v[u] * inv;
  }
}

// ---------------- V transpose: qkv fp32 -> Vt[384][64][224] fp32 (zero-padded) ----------------
__global__ __launch_bounds__(256) void v_transpose_f32(const float* __restrict__ qkv,
                                                       float* __restrict__ Vt) {
  int bh = blockIdx.y;
  int b = bh / 12, h = bh % 12;
  int j0 = blockIdx.x * 64;
  __shared__ float tbuf[64][65];
  int tid = threadIdx.x;
  int d = tid & 63;
  for (int jj = tid >> 6; jj < 64; jj += 4) {
    int j = j0 + jj;
    float val = 0.f;
    if (j < 197) val = qkv[(size_t)(b * 197 + j) * 2304 + 1536 + h * 64 + d];
    tbuf[jj][d] = val;
  }
  __syncthreads();
  int jl = tid & 63;
  int jc = j0 + jl;
  for (int dd = tid >> 6; dd < 64; dd += 4) {
    if (jc < 224) Vt[((size_t)bh * 64 + dd) * 224 + jc] = tbuf[jl][dd];
  }
}

// ---------------- head: out[32,1000] = cls_ln @ head_w^T + head_b (exact fp32) ----------------
__global__ __launch_bounds__(256) void head_kernel(const float* __restrict__ cls,
                                                   const float* __restrict__ hw,
                                                   const float* __restrict__ hb,
                                                   float* __restrict__ out) {
  int b = blockIdx.x;
  __shared__ float xr[768];
  for (int d = threadIdx.x; d < 768; d += 256) xr[d] = cls[(size_t)b * 768 + d];
  __syncthreads();
  for (int n = threadIdx.x; n < 1000; n += 256) {
    const float* wr = hw + (size_t)n * 768;
    float acc = 0.f;
    for (int d = 0; d < 768; d += 4) {
      float4 xx = *(const float4*)(xr + d);
      float4 ww = *(const float4*)(wr + d);
      acc += xx.x * ww.x + xx.y * ww.y + xx.z * ww.z + xx.w * ww.w;
    }
    out[(size_t)b * 1000 + n] = acc + hb[n];
  }
}

extern "C" void kernel_launch(void* const* d_in, const int* in_sizes, int n_in,
                              void* d_out, int out_size, void* d_ws, size_t ws_size,
                              hipStream_t stream) {
  const float* x       = (const float*)d_in[0];
  const float* patch_w = (const float*)d_in[1];
  const float* patch_b = (const float*)d_in[2];
  const float* pos     = (const float*)d_in[3];
  const float* cls     = (const float*)d_in[4];
  const float* ln1_w   = (const float*)d_in[5];
  const float* ln1_b   = (const float*)d_in[6];
  const float* qkv_w   = (const float*)d_in[7];
  const float* qkv_b   = (const float*)d_in[8];
  const float* proj_w  = (const float*)d_in[9];
  const float* proj_b  = (const float*)d_in[10];
  const float* ln2_w   = (const float*)d_in[11];
  const float* ln2_b   = (const float*)d_in[12];
  const float* fc1_w   = (const float*)d_in[13];
  const float* fc1_b   = (const float*)d_in[14];
  const float* fc2_w   = (const float*)d_in[15];
  const float* fc2_b   = (const float*)d_in[16];
  const float* ln_w    = (const float*)d_in[17];
  const float* ln_b    = (const float*)d_in[18];
  const float* head_w  = (const float*)d_in[19];
  const float* head_b  = (const float*)d_in[20];
  float* out = (float*)d_out;

  char* base = (char*)d_ws;
  size_t off = 0;
  auto alloc = [&](size_t bytes) {
    void* p = base + off;
    off = (off + bytes + 255) & ~(size_t)255;
    return p;
  };

  // ~225 MB total
  float* h            = (float*)alloc(6304ull * 768 * 4);
  unsigned short* yhi = (unsigned short*)alloc(6304ull * 768 * 2);
  unsigned short* ylo = (unsigned short*)alloc(6304ull * 768 * 2);
  float* qkvb         = (float*)alloc(6304ull * 2304 * 4);
  float* Vt           = (float*)alloc(384ull * 64 * 224 * 4);
  float* o            = (float*)alloc(6304ull * 768 * 4);
  float* cls_ln       = (float*)alloc(32ull * 768 * 4);
  unsigned short* whi = (unsigned short*)alloc(2359296ull * 2);  // max weight 3072x768
  unsigned short* wlo = (unsigned short*)alloc(2359296ull * 2);
  // overlapped region (77.5 MB): prologue {patches hi/lo, pe} / attn {Sb -> o hi/lo} / MLP {mb hi/lo}
  char* R = (char*)alloc(6304ull * 3072 * 4);
  unsigned short* p_hi  = (unsigned short*)R;
  unsigned short* p_lo  = p_hi + 6272ull * 768;
  float*          pe    = (float*)(R + 6272ull * 768 * 4);
  float*          Sb    = (float*)R;                       // [384][197][224]
  unsigned short* o_hi  = (unsigned short*)R;              // after Sb dead
  unsigned short* o_lo  = o_hi + 6304ull * 768;
  unsigned short* mb_hi = (unsigned short*)R;              // after o_hi/lo dead
  unsigned short* mb_lo = mb_hi + 6304ull * 3072;

  // ---- patch embed (bf16x3 MFMA) ----
  im2col_split<<<4704, 256, 0, stream>>>(x, p_hi, p_lo);
  split_f32<<<576, 256, 0, stream>>>(patch_w, whi, wlo, 147456);
  gemm_bf16x3<<<dim3(6, 49), 256, 0, stream>>>(
      p_hi, p_lo, whi, wlo, patch_b, nullptr, pe, nullptr, nullptr,
      6272, 768, 768, 768, 768, 768, 2);
  assemble_h<<<4728, 256, 0, stream>>>(pe, pos, cls, h);

  // ---- transformer layers ----
  for (int l = 0; l < 12; ++l) {
    layernorm_split<<<6304, 256, 0, stream>>>(h, ln1_w + l * 768, ln1_b + l * 768, yhi, ylo);
    split_f32<<<1728, 256, 0, stream>>>(qkv_w + (size_t)l * 1769472, whi, wlo, 442368);
    gemm_bf16x3<<<dim3(18, 50), 256, 0, stream>>>(
        yhi, ylo, whi, wlo, qkv_b + l * 2304, nullptr, qkvb, nullptr, nullptr,
        6304, 2304, 768, 768, 768, 2304, 2);
    v_transpose_f32<<<dim3(4, 384), 256, 0, stream>>>(qkvb, Vt);
    // scores: per (b,h): Q[197,64] @ K[197,64]^T -> Sb  (fp32 anchor path)
    gemm_f32<<<dim3(4, 4, 384), 256, 0, stream>>>(
        qkvb, qkvb + 768, nullptr, nullptr, Sb,
        197, 197, 64, 2304, 2304, 224,
        197LL * 2304, 64LL, 197LL * 2304, 64LL, 12LL * 44128, 44128LL, 12, 0);
    softmax_f32<<<75648, 64, 0, stream>>>(Sb);
    // P @ V: per (b,h): [197,224] @ Vt[64,224]^T -> o[b,t,h*64+d]
    gemm_f32<<<dim3(1, 4, 384), 256, 0, stream>>>(
        Sb, Vt, nullptr, nullptr, o,
        197, 64, 224, 224, 224, 768,
        12LL * 44128, 44128LL, 12LL * 14336, 14336LL, 197LL * 768, 64LL, 12, 0);
    split_f32<<<4728, 256, 0, stream>>>(o, o_hi, o_lo, 1210368);
    split_f32<<<576, 256, 0, stream>>>(proj_w + (size_t)l * 589824, whi, wlo, 147456);
    gemm_bf16x3<<<dim3(6, 50), 256, 0, stream>>>(
        o_hi, o_lo, whi, wlo, proj_b + l * 768, h, h, nullptr, nullptr,
        6304, 768, 768, 768, 768, 768, 2 | 4);
    layernorm_split<<<6304, 256, 0, stream>>>(h, ln2_w + l * 768, ln2_b + l * 768, yhi, ylo);
    split_f32<<<2304, 256, 0, stream>>>(fc1_w + (size_t)l * 2359296, whi, wlo, 589824);
    gemm_bf16x3<<<dim3(24, 50), 256, 0, stream>>>(
        yhi, ylo, whi, wlo, fc1_b + l * 3072, nullptr, nullptr, mb_hi, mb_lo,
        6304, 3072, 768, 768, 768, 3072, 2 | 1 | 8);
    split_f32<<<2304, 256, 0, stream>>>(fc2_w + (size_t)l * 2359296, whi, wlo, 589824);
    gemm_bf16x3<<<dim3(6, 50), 256, 0, stream>>>(
        mb_hi, mb_lo, whi, wlo, fc2_b + l * 768, h, h, nullptr, nullptr,
        6304, 768, 3072, 3072, 3072, 768, 2 | 4);
  }

  // ---- final LN (cls rows only) + head ----
  layernorm_f32<<<32, 256, 0, stream>>>(h, ln_w, ln_b, cls_ln, 197LL * 768);
  head_kernel<<<32, 256, 0, stream>>>(cls_ln, head_w, head_b, out);
}

// Round 5
// 8051.038 us; speedup vs baseline: 2.2043x; 1.0314x over previous
//
#include <hip/hip_runtime.h>

typedef __attribute__((ext_vector_type(8))) short bf16x8;   // 8 bf16 bit-patterns (4 VGPRs)
typedef __attribute__((ext_vector_type(4))) float f32x4;

// ---- round-to-nearest-even fp32 -> bf16, and the 2-term RNE split ----
__device__ __forceinline__ unsigned short bf_rne(float a) {
  unsigned int u = __float_as_uint(a);
  return (unsigned short)((u + 0x7fffu + ((u >> 16) & 1u)) >> 16);
}
__device__ __forceinline__ float from_bf(unsigned short h) {
  return __uint_as_float((unsigned int)h << 16);
}
__device__ __forceinline__ void split2(float x, unsigned short& h, unsigned short& l) {
  h = bf_rne(x);
  float lo = x - from_bf(h);   // exact (Sterbenz: hi within half-ulp of x)
  l = bf_rne(lo);
}
__device__ __forceinline__ unsigned int pack2(unsigned short a, unsigned short b) {
  return (unsigned int)a | ((unsigned int)b << 16);
}

// ---------------- im2col + bf16 hi/lo split: x[B,3,224,224] -> ph/pl[6272,768] ----------------
__global__ __launch_bounds__(256) void im2col_split(const float* __restrict__ x,
                                                    unsigned short* __restrict__ ph,
                                                    unsigned short* __restrict__ pl) {
  int idx = blockIdx.x * 256 + threadIdx.x;
  if (idx >= 6272 * 192) return;
  int k4 = idx % 192, r = idx / 192;
  int k = k4 * 4;
  int c = k >> 8, py = (k >> 4) & 15, px = k & 15;
  int t = r % 196, b = r / 196;
  int gy = t / 14, gx = t % 14;
  float4 f = *(const float4*)(x + (((size_t)(b * 3 + c) * 224 + gy * 16 + py) * 224 + gx * 16 + px));
  unsigned short h0, l0, h1, l1, h2, l2, h3, l3;
  split2(f.x, h0, l0); split2(f.y, h1, l1); split2(f.z, h2, l2); split2(f.w, h3, l3);
  uint2 hp, lp;
  hp.x = pack2(h0, h1); hp.y = pack2(h2, h3);
  lp.x = pack2(l0, l1); lp.y = pack2(l2, l3);
  *(uint2*)(ph + (size_t)r * 768 + k) = hp;
  *(uint2*)(pl + (size_t)r * 768 + k) = lp;
}

// ---------------- generic fp32 -> bf16 hi/lo split (weights, attention output) ----------------
__global__ __launch_bounds__(256) void split_f32(const float* __restrict__ in,
                                                 unsigned short* __restrict__ hi,
                                                 unsigned short* __restrict__ lo, int n4) {
  int i = blockIdx.x * 256 + threadIdx.x;
  if (i >= n4) return;
  float4 f = ((const float4*)in)[i];
  unsigned short h0, l0, h1, l1, h2, l2, h3, l3;
  split2(f.x, h0, l0); split2(f.y, h1, l1); split2(f.z, h2, l2); split2(f.w, h3, l3);
  uint2 hp, lp;
  hp.x = pack2(h0, h1); hp.y = pack2(h2, h3);
  lp.x = pack2(l0, l1); lp.y = pack2(l2, l3);
  *(uint2*)(hi + (size_t)i * 4) = hp;
  *(uint2*)(lo + (size_t)i * 4) = lp;
}

// ---------------- assemble h[6304,768] fp32 = [cls | pe+pos] ----------------
__global__ __launch_bounds__(256) void assemble_h(const float* __restrict__ pe,
                                                  const float* __restrict__ pos,
                                                  const float* __restrict__ cls,
                                                  float* __restrict__ h) {
  int idx = blockIdx.x * 256 + threadIdx.x;
  if (idx >= 6304 * 192) return;
  int d4 = idx % 192, row = idx / 192;
  int t = row % 197, b = row / 197;
  int d = d4 * 4;
  float4 v;
  if (t == 0) {
    v = *(const float4*)(cls + d);
  } else {
    v = *(const float4*)(pe + ((size_t)(b * 196 + (t - 1))) * 768 + d);
    float4 p = *(const float4*)(pos + (size_t)(t - 1) * 768 + d);
    v.x += p.x; v.y += p.y; v.z += p.z; v.w += p.w;
  }
  *(float4*)(h + (size_t)row * 768 + d) = v;
}

// ---------------- LayerNorm (row=768) fp32 -> fp32 (final LN only) ----------------
__global__ __launch_bounds__(256) void layernorm_f32(const float* __restrict__ x,
                                                     const float* __restrict__ w,
                                                     const float* __restrict__ b,
                                                     float* __restrict__ y, long long xstride) {
  long long row = blockIdx.x;
  const float* xr = x + row * xstride;
  int tid = threadIdx.x;
  float v0 = xr[tid], v1 = xr[tid + 256], v2 = xr[tid + 512];
  float s = v0 + v1 + v2;
  float ss = v0 * v0 + v1 * v1 + v2 * v2;
  for (int off = 32; off; off >>= 1) {
    s += __shfl_xor(s, off);
    ss += __shfl_xor(ss, off);
  }
  __shared__ float red[8];
  int wv = tid >> 6;
  if ((tid & 63) == 0) { red[wv] = s; red[wv + 4] = ss; }
  __syncthreads();
  s = red[0] + red[1] + red[2] + red[3];
  ss = red[4] + red[5] + red[6] + red[7];
  float mean = s * (1.0f / 768.0f);
  float var = ss * (1.0f / 768.0f) - mean * mean;
  float rstd = rsqrtf(var + 1e-5f);
  float* yr = y + row * 768;
  yr[tid] = (v0 - mean) * rstd * w[tid] + b[tid];
  yr[tid + 256] = (v1 - mean) * rstd * w[tid + 256] + b[tid + 256];
  yr[tid + 512] = (v2 - mean) * rstd * w[tid + 512] + b[tid + 512];
}

// ---------------- LayerNorm (row=768) fp32 -> bf16 hi/lo split ----------------
__global__ __launch_bounds__(256) void layernorm_split(const float* __restrict__ x,
                                                       const float* __restrict__ w,
                                                       const float* __restrict__ b,
                                                       unsigned short* __restrict__ yh,
                                                       unsigned short* __restrict__ yl) {
  long long row = blockIdx.x;
  const float* xr = x + row * 768;
  int tid = threadIdx.x;
  float v0 = xr[tid], v1 = xr[tid + 256], v2 = xr[tid + 512];
  float s = v0 + v1 + v2;
  float ss = v0 * v0 + v1 * v1 + v2 * v2;
  for (int off = 32; off; off >>= 1) {
    s += __shfl_xor(s, off);
    ss += __shfl_xor(ss, off);
  }
  __shared__ float red[8];
  int wv = tid >> 6;
  if ((tid & 63) == 0) { red[wv] = s; red[wv + 4] = ss; }
  __syncthreads();
  s = red[0] + red[1] + red[2] + red[3];
  ss = red[4] + red[5] + red[6] + red[7];
  float mean = s * (1.0f / 768.0f);
  float var = ss * (1.0f / 768.0f) - mean * mean;
  float rstd = rsqrtf(var + 1e-5f);
  unsigned short* yhr = yh + row * 768;
  unsigned short* ylr = yl + row * 768;
#pragma unroll
  for (int u = 0; u < 3; u++) {
    int c = tid + u * 256;
    float v = (u == 0 ? v0 : (u == 1 ? v1 : v2));
    float o = (v - mean) * rstd * w[c] + b[c];
    unsigned short hh, ll;
    split2(o, hh, ll);
    yhr[c] = hh;
    ylr[c] = ll;
  }
}

// ---------------- bf16x3 MFMA GEMM: C = act(A@W^T + bias) (+Res) ----------------
// A = Ah+Al [M,lda] bf16 hi/lo; W = Wh+Wl [N,ldw]; emulated-fp32 via 3 MFMA products.
// flags: 1=gelu, 2=bias, 4=residual, 8=split bf16 output (Chi/Clo) instead of fp32 C.
// Tile 128x128, BK=32, 4 waves, each wave owns a 64x64 quadrant = 4x4 16x16 frags.
// Round-2 verified LDS layout + T14 reg-staged prefetch: global loads for tile t+1 are
// issued into registers BEFORE the MFMA block of tile t (HBM latency hides under compute);
// the next iteration's ds_write consumes them after the barrier. No global_load_lds DMA.
__global__ __launch_bounds__(256, 2) void gemm_bf16x3(
    const unsigned short* __restrict__ Ah, const unsigned short* __restrict__ Al,
    const unsigned short* __restrict__ Wh, const unsigned short* __restrict__ Wl,
    const float* __restrict__ bias, const float* __restrict__ Res,
    float* __restrict__ C, unsigned short* __restrict__ Chi, unsigned short* __restrict__ Clo,
    int M, int N, int K, int lda, int ldw, int ldc, int flags) {
  __shared__ __align__(16) unsigned short As_h[128 * 32], As_l[128 * 32], Bs_h[128 * 32], Bs_l[128 * 32];
  const int tid = threadIdx.x;
  const int lane = tid & 63, wv = tid >> 6;
  const int wr = wv >> 1, wc = wv & 1;
  const int m0 = blockIdx.y * 128, n0 = blockIdx.x * 128;

  // staging map: thread covers (row, slot) and (row+64, slot); slot = 8 contiguous bf16.
  const int srow = tid >> 2, ssl = tid & 3;
  int arow0 = m0 + srow;      if (arow0 >= M) arow0 = M - 1;
  int arow1 = m0 + srow + 64; if (arow1 >= M) arow1 = M - 1;
  const int brow0 = n0 + srow, brow1 = n0 + srow + 64;   // N is always a multiple of 128
  const unsigned short* pAh0 = Ah + (size_t)arow0 * lda + ssl * 8;
  const unsigned short* pAh1 = Ah + (size_t)arow1 * lda + ssl * 8;
  const unsigned short* pAl0 = Al + (size_t)arow0 * lda + ssl * 8;
  const unsigned short* pAl1 = Al + (size_t)arow1 * lda + ssl * 8;
  const unsigned short* pBh0 = Wh + (size_t)brow0 * ldw + ssl * 8;
  const unsigned short* pBh1 = Wh + (size_t)brow1 * ldw + ssl * 8;
  const unsigned short* pBl0 = Wl + (size_t)brow0 * ldw + ssl * 8;
  const unsigned short* pBl1 = Wl + (size_t)brow1 * ldw + ssl * 8;
  const int ps = ssl ^ ((srow >> 1) & 3);          // physical slot (same for row and row+64)
  const int w0 = srow * 32 + ps * 8, w1 = w0 + 64 * 32;

  // fragment read offsets (ushort units): row*32 + (kg^sx)*8, sx=((lane&15)>>1)&3
  const int kg = lane >> 4, r15 = lane & 15;
  const int fo = r15 * 32 + ((kg ^ ((r15 >> 1) & 3)) * 8);
  int aoff[4], boff[4];
#pragma unroll
  for (int i = 0; i < 4; i++) {
    aoff[i] = (wr * 64 + i * 16) * 32 + fo;
    boff[i] = (wc * 64 + i * 16) * 32 + fo;
  }

  f32x4 acc[4][4] = {};

  // staging registers (in flight across the MFMA phase)
  uint4 rAh0, rAh1, rAl0, rAl1, rBh0, rBh1, rBl0, rBl1;
  auto load_tile = [&](int k0) {
    rAh0 = *(const uint4*)(pAh0 + k0);
    rAh1 = *(const uint4*)(pAh1 + k0);
    rAl0 = *(const uint4*)(pAl0 + k0);
    rAl1 = *(const uint4*)(pAl1 + k0);
    rBh0 = *(const uint4*)(pBh0 + k0);
    rBh1 = *(const uint4*)(pBh1 + k0);
    rBl0 = *(const uint4*)(pBl0 + k0);
    rBl1 = *(const uint4*)(pBl1 + k0);
  };

  load_tile(0);
  const int NT = K >> 5;
  for (int t = 0; t < NT; ++t) {
    __syncthreads();                       // prev iteration's LDS reads done (no-op at t=0)
    *(uint4*)&As_h[w0] = rAh0; *(uint4*)&As_h[w1] = rAh1;   // vmcnt wait lands here
    *(uint4*)&As_l[w0] = rAl0; *(uint4*)&As_l[w1] = rAl1;
    *(uint4*)&Bs_h[w0] = rBh0; *(uint4*)&Bs_h[w1] = rBh1;
    *(uint4*)&Bs_l[w0] = rBl0; *(uint4*)&Bs_l[w1] = rBl1;
    __syncthreads();
    if (t + 1 < NT) load_tile((t + 1) << 5);   // prefetch: latency hides under MFMA below
    bf16x8 ah[4], al[4], bh[4], bl[4];
#pragma unroll
    for (int i = 0; i < 4; i++) {
      ah[i] = *(const bf16x8*)&As_h[aoff[i]];
      al[i] = *(const bf16x8*)&As_l[aoff[i]];
    }
#pragma unroll
    for (int j = 0; j < 4; j++) {
      bh[j] = *(const bf16x8*)&Bs_h[boff[j]];
      bl[j] = *(const bf16x8*)&Bs_l[boff[j]];
    }
#pragma unroll
    for (int i = 0; i < 4; i++)
#pragma unroll
      for (int j = 0; j < 4; j++) {
        acc[i][j] = __builtin_amdgcn_mfma_f32_16x16x32_bf16(ah[i], bh[j], acc[i][j], 0, 0, 0);
        acc[i][j] = __builtin_amdgcn_mfma_f32_16x16x32_bf16(ah[i], bl[j], acc[i][j], 0, 0, 0);
        acc[i][j] = __builtin_amdgcn_mfma_f32_16x16x32_bf16(al[i], bh[j], acc[i][j], 0, 0, 0);
      }
  }

  const bool gelu = flags & 1, hasb = flags & 2, hasr = flags & 4, sout = flags & 8;
#pragma unroll
  for (int j = 0; j < 4; j++) {
    int n = n0 + wc * 64 + j * 16 + r15;              // C/D col = lane&15
    float bj = hasb ? bias[n] : 0.0f;
#pragma unroll
    for (int i = 0; i < 4; i++) {
      int mbase = m0 + wr * 64 + i * 16 + kg * 4;     // C/D row = (lane>>4)*4 + reg
#pragma unroll
      for (int rr = 0; rr < 4; rr++) {
        int m = mbase + rr;
        if (m >= M) continue;
        float v = acc[i][j][rr] + bj;
        if (gelu) v = 0.5f * v * (1.0f + erff(v * 0.70710678118f));
        if (hasr) v += Res[(size_t)m * ldc + n];
        if (sout) {
          unsigned short hh, ll;
          split2(v, hh, ll);
          Chi[(size_t)m * ldc + n] = hh;
          Clo[(size_t)m * ldc + n] = ll;
        } else {
          C[(size_t)m * ldc + n] = v;
        }
      }
    }
  }
}

// ---------------- generic batched NT GEMM, pure fp32 (attention scores / PV) ----------------
__global__ __launch_bounds__(256) void gemm_f32(
    const float* A, const float* W, const float* bias, const float* Res, float* C,
    int M, int N, int K, int lda, int ldw, int ldc,
    long long offA1, long long offA2, long long offW1, long long offW2,
    long long offC1, long long offC2, int Hdiv, int flags) {
  int bz = blockIdx.z;
  int zh = bz / Hdiv, zl = bz - zh * Hdiv;
  A += (size_t)zh * offA1 + (size_t)zl * offA2;
  W += (size_t)zh * offW1 + (size_t)zl * offW2;
  long long coff = (long long)zh * offC1 + (long long)zl * offC2;

  __shared__ float As[16][68];
  __shared__ float Ws[16][68];
  int tid = threadIdx.x;
  int m0 = blockIdx.y * 64, n0 = blockIdx.x * 64;
  int tx = tid & 15, ty = tid >> 4;
  float acc[4][4] = {};
  int r = tid >> 2, c4 = (tid & 3) * 4;

  for (int k0 = 0; k0 < K; k0 += 16) {
    float4 av = {0.f, 0.f, 0.f, 0.f}, wv = {0.f, 0.f, 0.f, 0.f};
    if (m0 + r < M) av = *(const float4*)(A + (size_t)(m0 + r) * lda + k0 + c4);
    if (n0 + r < N) wv = *(const float4*)(W + (size_t)(n0 + r) * ldw + k0 + c4);
    __syncthreads();
    As[c4 + 0][r] = av.x; As[c4 + 1][r] = av.y; As[c4 + 2][r] = av.z; As[c4 + 3][r] = av.w;
    Ws[c4 + 0][r] = wv.x; Ws[c4 + 1][r] = wv.y; Ws[c4 + 2][r] = wv.z; Ws[c4 + 3][r] = wv.w;
    __syncthreads();
#pragma unroll
    for (int kk = 0; kk < 16; kk++) {
      float a[4], b[4];
#pragma unroll
      for (int i = 0; i < 4; i++) a[i] = As[kk][ty * 4 + i];
#pragma unroll
      for (int j = 0; j < 4; j++) b[j] = Ws[kk][tx * 4 + j];
#pragma unroll
      for (int i = 0; i < 4; i++)
#pragma unroll
        for (int j = 0; j < 4; j++) acc[i][j] += a[i] * b[j];
    }
  }

  bool gelu = flags & 1, hasb = flags & 2, hasr = flags & 4;
#pragma unroll
  for (int i = 0; i < 4; i++) {
    int m = m0 + ty * 4 + i;
    if (m >= M) continue;
#pragma unroll
    for (int j = 0; j < 4; j++) {
      int n = n0 + tx * 4 + j;
      if (n >= N) continue;
      float v = acc[i][j];
      if (hasb) v += bias[n];
      if (gelu) v = 0.5f * v * (1.0f + erff(v * 0.70710678118f));
      if (hasr) v += Res[coff + (size_t)m * ldc + n];
      C[coff + (size_t)m * ldc + n] = v;
    }
  }
}

// ---------------- softmax in-place on S[384*197,224] fp32 ----------------
__global__ __launch_bounds__(64) void softmax_f32(float* __restrict__ S) {
  size_t row = blockIdx.x;
  float* s = S + row * 224;
  int t = threadIdx.x;
  float v[4];
  float mx = -1e30f;
#pragma unroll
  for (int u = 0; u < 4; u++) {
    int j = t + u * 64;
    v[u] = (j < 197) ? s[j] * 8.0f : -1e30f;  // faithful bug: scores * sqrt(head_dim)
    mx = fmaxf(mx, v[u]);
  }
  for (int off = 32; off; off >>= 1) mx = fmaxf(mx, __shfl_xor(mx, off));
  float sum = 0.f;
#pragma unroll
  for (int u = 0; u < 4; u++) {
    int j = t + u * 64;
    v[u] = (j < 197) ? __expf(v[u] - mx) : 0.f;
    sum += v[u];
  }
  for (int off = 32; off; off >>= 1) sum += __shfl_xor(sum, off);
  float inv = 1.0f / sum;
#pragma unroll
  for (int u = 0; u < 4; u++) {
    int j = t + u * 64;
    if (j < 224) s[j] = v[u] * inv;
  }
}

// ---------------- V transpose: qkv fp32 -> Vt[384][64][224] fp32 (zero-padded) ----------------
__global__ __launch_bounds__(256) void v_transpose_f32(const float* __restrict__ qkv,
                                                       float* __restrict__ Vt) {
  int bh = blockIdx.y;
  int b = bh / 12, h = bh % 12;
  int j0 = blockIdx.x * 64;
  __shared__ float tbuf[64][65];
  int tid = threadIdx.x;
  int d = tid & 63;
  for (int jj = tid >> 6; jj < 64; jj += 4) {
    int j = j0 + jj;
    float val = 0.f;
    if (j < 197) val = qkv[(size_t)(b * 197 + j) * 2304 + 1536 + h * 64 + d];
    tbuf[jj][d] = val;
  }
  __syncthreads();
  int jl = tid & 63;
  int jc = j0 + jl;
  for (int dd = tid >> 6; dd < 64; dd += 4) {
    if (jc < 224) Vt[((size_t)bh * 64 + dd) * 224 + jc] = tbuf[jl][dd];
  }
}

// ---------------- head: out[32,1000] = cls_ln @ head_w^T + head_b (exact fp32) ----------------
__global__ __launch_bounds__(256) void head_kernel(const float* __restrict__ cls,
                                                   const float* __restrict__ hw,
                                                   const float* __restrict__ hb,
                                                   float* __restrict__ out) {
  int b = blockIdx.x;
  __shared__ float xr[768];
  for (int d = threadIdx.x; d < 768; d += 256) xr[d] = cls[(size_t)b * 768 + d];
  __syncthreads();
  for (int n = threadIdx.x; n < 1000; n += 256) {
    const float* wr = hw + (size_t)n * 768;
    float acc = 0.f;
    for (int d = 0; d < 768; d += 4) {
      float4 xx = *(const float4*)(xr + d);
      float4 ww = *(const float4*)(wr + d);
      acc += xx.x * ww.x + xx.y * ww.y + xx.z * ww.z + xx.w * ww.w;
    }
    out[(size_t)b * 1000 + n] = acc + hb[n];
  }
}

extern "C" void kernel_launch(void* const* d_in, const int* in_sizes, int n_in,
                              void* d_out, int out_size, void* d_ws, size_t ws_size,
                              hipStream_t stream) {
  const float* x       = (const float*)d_in[0];
  const float* patch_w = (const float*)d_in[1];
  const float* patch_b = (const float*)d_in[2];
  const float* pos     = (const float*)d_in[3];
  const float* cls     = (const float*)d_in[4];
  const float* ln1_w   = (const float*)d_in[5];
  const float* ln1_b   = (const float*)d_in[6];
  const float* qkv_w   = (const float*)d_in[7];
  const float* qkv_b   = (const float*)d_in[8];
  const float* proj_w  = (const float*)d_in[9];
  const float* proj_b  = (const float*)d_in[10];
  const float* ln2_w   = (const float*)d_in[11];
  const float* ln2_b   = (const float*)d_in[12];
  const float* fc1_w   = (const float*)d_in[13];
  const float* fc1_b   = (const float*)d_in[14];
  const float* fc2_w   = (const float*)d_in[15];
  const float* fc2_b   = (const float*)d_in[16];
  const float* ln_w    = (const float*)d_in[17];
  const float* ln_b    = (const float*)d_in[18];
  const float* head_w  = (const float*)d_in[19];
  const float* head_b  = (const float*)d_in[20];
  float* out = (float*)d_out;

  char* base = (char*)d_ws;
  size_t off = 0;
  auto alloc = [&](size_t bytes) {
    void* p = base + off;
    off = (off + bytes + 255) & ~(size_t)255;
    return p;
  };

  // ~225 MB total
  float* h            = (float*)alloc(6304ull * 768 * 4);
  unsigned short* yhi = (unsigned short*)alloc(6304ull * 768 * 2);
  unsigned short* ylo = (unsigned short*)alloc(6304ull * 768 * 2);
  float* qkvb         = (float*)alloc(6304ull * 2304 * 4);
  float* Vt           = (float*)alloc(384ull * 64 * 224 * 4);
  float* o            = (float*)alloc(6304ull * 768 * 4);
  float* cls_ln       = (float*)alloc(32ull * 768 * 4);
  unsigned short* whi = (unsigned short*)alloc(2359296ull * 2);  // max weight 3072x768
  unsigned short* wlo = (unsigned short*)alloc(2359296ull * 2);
  // overlapped region (77.5 MB): prologue {patches hi/lo, pe} / attn {Sb -> o hi/lo} / MLP {mb hi/lo}
  char* R = (char*)alloc(6304ull * 3072 * 4);
  unsigned short* p_hi  = (unsigned short*)R;
  unsigned short* p_lo  = p_hi + 6272ull * 768;
  float*          pe    = (float*)(R + 6272ull * 768 * 4);
  float*          Sb    = (float*)R;                       // [384][197][224]
  unsigned short* o_hi  = (unsigned short*)R;              // after Sb dead
  unsigned short* o_lo  = o_hi + 6304ull * 768;
  unsigned short* mb_hi = (unsigned short*)R;              // after o_hi/lo dead
  unsigned short* mb_lo = mb_hi + 6304ull * 3072;

  // ---- patch embed (bf16x3 MFMA) ----
  im2col_split<<<4704, 256, 0, stream>>>(x, p_hi, p_lo);
  split_f32<<<576, 256, 0, stream>>>(patch_w, whi, wlo, 147456);
  gemm_bf16x3<<<dim3(6, 49), 256, 0, stream>>>(
      p_hi, p_lo, whi, wlo, patch_b, nullptr, pe, nullptr, nullptr,
      6272, 768, 768, 768, 768, 768, 2);
  assemble_h<<<4728, 256, 0, stream>>>(pe, pos, cls, h);

  // ---- transformer layers ----
  for (int l = 0; l < 12; ++l) {
    layernorm_split<<<6304, 256, 0, stream>>>(h, ln1_w + l * 768, ln1_b + l * 768, yhi, ylo);
    split_f32<<<1728, 256, 0, stream>>>(qkv_w + (size_t)l * 1769472, whi, wlo, 442368);
    gemm_bf16x3<<<dim3(18, 50), 256, 0, stream>>>(
        yhi, ylo, whi, wlo, qkv_b + l * 2304, nullptr, qkvb, nullptr, nullptr,
        6304, 2304, 768, 768, 768, 2304, 2);
    v_transpose_f32<<<dim3(4, 384), 256, 0, stream>>>(qkvb, Vt);
    // scores: per (b,h): Q[197,64] @ K[197,64]^T -> Sb  (fp32 anchor path)
    gemm_f32<<<dim3(4, 4, 384), 256, 0, stream>>>(
        qkvb, qkvb + 768, nullptr, nullptr, Sb,
        197, 197, 64, 2304, 2304, 224,
        197LL * 2304, 64LL, 197LL * 2304, 64LL, 12LL * 44128, 44128LL, 12, 0);
    softmax_f32<<<75648, 64, 0, stream>>>(Sb);
    // P @ V: per (b,h): [197,224] @ Vt[64,224]^T -> o[b,t,h*64+d]
    gemm_f32<<<dim3(1, 4, 384), 256, 0, stream>>>(
        Sb, Vt, nullptr, nullptr, o,
        197, 64, 224, 224, 224, 768,
        12LL * 44128, 44128LL, 12LL * 14336, 14336LL, 197LL * 768, 64LL, 12, 0);
    split_f32<<<4728, 256, 0, stream>>>(o, o_hi, o_lo, 1210368);
    split_f32<<<576, 256, 0, stream>>>(proj_w + (size_t)l * 589824, whi, wlo, 147456);
    gemm_bf16x3<<<dim3(6, 50), 256, 0, stream>>>(
        o_hi, o_lo, whi, wlo, proj_b + l * 768, h, h, nullptr, nullptr,
        6304, 768, 768, 768, 768, 768, 2 | 4);
    layernorm_split<<<6304, 256, 0, stream>>>(h, ln2_w + l * 768, ln2_b + l * 768, yhi, ylo);
    split_f32<<<2304, 256, 0, stream>>>(fc1_w + (size_t)l * 2359296, whi, wlo, 589824);
    gemm_bf16x3<<<dim3(24, 50), 256, 0, stream>>>(
        yhi, ylo, whi, wlo, fc1_b + l * 3072, nullptr, nullptr, mb_hi, mb_lo,
        6304, 3072, 768, 768, 768, 3072, 2 | 1 | 8);
    split_f32<<<2304, 256, 0, stream>>>(fc2_w + (size_t)l * 2359296, whi, wlo, 589824);
    gemm_bf16x3<<<dim3(6, 50), 256, 0, stream>>>(
        mb_hi, mb_lo, whi, wlo, fc2_b + l * 768, h, h, nullptr, nullptr,
        6304, 768, 3072, 3072, 3072, 768, 2 | 4);
  }

  // ---- final LN (cls rows only) + head ----
  layernorm_f32<<<32, 256, 0, stream>>>(h, ln_w, ln_b, cls_ln, 197LL * 768);
  head_kernel<<<32, 256, 0, stream>>>(cls_ln, head_w, head_b, out);
}